// Round 1
// 170.020 us; speedup vs baseline: 1.0268x; 1.0268x over previous
//
#include <hip/hip_runtime.h>

#define BATCH 8
#define SEQ   2048
#define EMB   1024
#define HD    64
#define HEADS 16
#define BS    (BATCH * SEQ)
#define LOG2E 1.4426950408889634f

typedef _Float16 half8 __attribute__((ext_vector_type(8)));
typedef _Float16 half4 __attribute__((ext_vector_type(4)));
typedef float    f32x4 __attribute__((ext_vector_type(4)));

__device__ __forceinline__ float fexp2(float x) {
#if __has_builtin(__builtin_amdgcn_exp2f)
    return __builtin_amdgcn_exp2f(x);
#else
    return exp2f(x);
#endif
}

__device__ __forceinline__ float frcp(float x) {
#if __has_builtin(__builtin_amdgcn_rcpf)
    return __builtin_amdgcn_rcpf(x);
#else
    return 1.0f / x;
#endif
}

// async global->LDS DMA: lane i deposits its element at lds_base + i*size.
// lds_base must be wave-uniform; gsrc is per-lane.
__device__ __forceinline__ void dma16(void* lds_base, const void* gsrc) {
    __builtin_amdgcn_global_load_lds(
        (const __attribute__((address_space(1))) unsigned int*)gsrc,
        (__attribute__((address_space(3))) unsigned int*)lds_base, 16, 0, 0);
}

// ---------------- W -> fp16 (Wq pre-scaled by log2e: scores in log2 domain)
__global__ __launch_bounds__(256) void wcvt_kernel(
    const float* __restrict__ Wq, const float* __restrict__ Wk,
    const float* __restrict__ Wv, _Float16* __restrict__ Wh)
{
    const int m = blockIdx.y;
    const float* src = (m == 0) ? Wq : (m == 1) ? Wk : Wv;
    const float scale = (m == 0) ? LOG2E : 1.0f;
    const int idx = (blockIdx.x * 256 + threadIdx.x) * 8;
    float4 f0 = *(const float4*)(src + idx);
    float4 f1 = *(const float4*)(src + idx + 4);
    half8 h;
    h[0] = (_Float16)(f0.x * scale); h[1] = (_Float16)(f0.y * scale);
    h[2] = (_Float16)(f0.z * scale); h[3] = (_Float16)(f0.w * scale);
    h[4] = (_Float16)(f1.x * scale); h[5] = (_Float16)(f1.y * scale);
    h[6] = (_Float16)(f1.z * scale); h[7] = (_Float16)(f1.w * scale);
    *(half8*)(Wh + (size_t)m * 65536 + idx) = h;
}

// ---------------- QKV projection ----------------
// 512 blocks x 512 thr (8 waves). Block = 32 rows, 12 ctiles; wave: strip=(w&1),
// grp=(w>>1) -> 3 ctiles. x (f32) + W (fp16) chunks staged by DMA, double-buffered,
// XOR-swizzled 16B granules; ONE vmcnt drain per chunk at the barrier.
__global__ __launch_bounds__(512) void qkv_kernel(
    const float* __restrict__ x, const _Float16* __restrict__ Wh,
    _Float16* __restrict__ qh, _Float16* __restrict__ kh, _Float16* __restrict__ vpt)
{
    __shared__ __align__(16) char arena[65536];  // x: 2x8KB, W: 2x24KB
    const int t = threadIdx.x, lane = t & 63, wave = t >> 6;
    const int l15 = lane & 15, quad = lane >> 4;
    const int strip = wave & 1, grp = wave >> 1;
    const int row0 = blockIdx.x * 32;

    auto issue = [&](int buf, int k0) {
        #pragma unroll
        for (int jj = 0; jj < 4; ++jj) {
            const int j = wave * 4 + jj;
            if (j < 8) {           // x: 8 instrs, 4 rows x 16 f32-segs each
                const int row = j * 4 + (lane >> 4);
                const int logi = (lane & 15) ^ (row & 15);
                dma16((float*)(arena + buf * 8192) + j * 256,
                      x + (size_t)(row0 + row) * EMB + k0 + logi * 4);
            } else {               // W: 24 instrs, 8 dd-rows x 8 half-segs each
                const int jw = j - 8;
                const int dd = jw * 8 + (lane >> 3);
                const int logi = (lane & 7) ^ (dd & 7);
                dma16((_Float16*)(arena + 16384 + buf * 24576) + jw * 512,
                      Wh + (size_t)(dd >> 6) * 65536 + (size_t)(dd & 63) * EMB
                         + k0 + logi * 8);
            }
        }
    };

    issue(0, 0);
    __syncthreads();

    f32x4 acc[3] = {};
    const int xrow = strip * 16 + l15;
    for (int it = 0; it < 16; ++it) {
        const int buf = it & 1;
        if (it + 1 < 16) issue(buf ^ 1, (it + 1) * 64);
        const float* xb = (const float*)(arena + buf * 8192);
        const _Float16* wb = (const _Float16*)(arena + 16384 + buf * 24576);
        half8 a[2];
        #pragma unroll
        for (int kc = 0; kc < 2; ++kc) {
            const int s0 = kc * 8 + quad * 2;
            f32x4 u0 = *(const f32x4*)(xb + xrow * 64 + ((s0    ) ^ (l15 & 15)) * 4);
            f32x4 u1 = *(const f32x4*)(xb + xrow * 64 + ((s0 + 1) ^ (l15 & 15)) * 4);
            a[kc][0] = (_Float16)u0[0]; a[kc][1] = (_Float16)u0[1];
            a[kc][2] = (_Float16)u0[2]; a[kc][3] = (_Float16)u0[3];
            a[kc][4] = (_Float16)u1[0]; a[kc][5] = (_Float16)u1[1];
            a[kc][6] = (_Float16)u1[2]; a[kc][7] = (_Float16)u1[3];
        }
        #pragma unroll
        for (int j = 0; j < 3; ++j) {
            const int dd = (grp * 3 + j) * 16 + l15;
            #pragma unroll
            for (int kc = 0; kc < 2; ++kc) {
                half8 bfr = *(const half8*)(wb + dd * 64
                              + (((kc * 4 + quad) ^ (l15 & 7)) * 8));
                acc[j] = __builtin_amdgcn_mfma_f32_16x16x32_f16(a[kc], bfr, acc[j], 0, 0, 0);
            }
        }
        __syncthreads();
    }

    #pragma unroll
    for (int j = 0; j < 3; ++j) {
        const int c = grp * 3 + j, m = c >> 2, n = c & 3;
        if (m < 2) {
            _Float16* __restrict__ dst = (m == 0) ? qh : kh;
            #pragma unroll
            for (int r = 0; r < 4; ++r)
                dst[(size_t)(row0 + strip * 16 + quad * 4 + r) * HD + n * 16 + l15] =
                    (_Float16)acc[j][r];
        } else {
            const int rg = row0 + strip * 16 + quad * 4;
            const int b = rg >> 11, s = rg & 2047;
            half4 h;
            h[0] = (_Float16)acc[j][0]; h[1] = (_Float16)acc[j][1];
            h[2] = (_Float16)acc[j][2]; h[3] = (_Float16)acc[j][3];
            *(half4*)(vpt + ((size_t)b * HD + n * 16 + l15) * SEQ + s) = h;
        }
    }
}

// ---------------- Column-softmax partial denominators ----------------
// grid (64,8,2) x 256 thr (4 waves). Block = 32 keys (A-frags held in regs);
// z = query-half: 16 DMA'd chunks of 64 queries; wave w -> queries w*16 of chunk.
// Writes RAW partial sums l_part[z][b][key] (reciprocal taken in out_kernel).
__global__ __launch_bounds__(256) void stats_kernel(
    const _Float16* __restrict__ qh, const _Float16* __restrict__ kh,
    float* __restrict__ l_part)
{
    __shared__ __align__(16) char arena[16384];  // q: 2x8KB
    __shared__ float red[4][32];
    const int t = threadIdx.x, lane = t & 63, wave = t >> 6;
    const int l15 = lane & 15, quad = lane >> 4;
    const int b = blockIdx.y, c0 = blockIdx.x * 32, z = blockIdx.z;
    const int qbase = z * 1024;

    half8 ka[2][2];
    #pragma unroll
    for (int kt = 0; kt < 2; ++kt) {
        const _Float16* kp = kh + ((size_t)b * SEQ + c0 + kt * 16 + l15) * HD + quad * 8;
        ka[kt][0] = *(const half8*)(kp);
        ka[kt][1] = *(const half8*)(kp + 32);
    }

    auto issue = [&](int buf, int q0) {
        #pragma unroll
        for (int jj = 0; jj < 2; ++jj) {
            const int j = wave * 2 + jj;
            const int qq = j * 8 + (lane >> 3);
            const int logi = (lane & 7) ^ (qq & 7);
            dma16((_Float16*)(arena + buf * 8192) + j * 512,
                  qh + ((size_t)b * SEQ + q0 + qq) * HD + logi * 8);
        }
    };

    issue(0, qbase);
    __syncthreads();

    float csum[2][4] = {};
    const int qrow = wave * 16 + l15;
    for (int it = 0; it < 16; ++it) {
        const int buf = it & 1;
        if (it + 1 < 16) issue(buf ^ 1, qbase + (it + 1) * 64);
        const _Float16* qb = (const _Float16*)(arena + buf * 8192);
        half8 bq[2];
        #pragma unroll
        for (int kc = 0; kc < 2; ++kc)
            bq[kc] = *(const half8*)(qb + qrow * 64
                        + (((kc * 4 + quad) ^ (l15 & 7)) * 8));
        f32x4 s0 = {}, s1 = {};
        s0 = __builtin_amdgcn_mfma_f32_16x16x32_f16(ka[0][0], bq[0], s0, 0, 0, 0);
        s0 = __builtin_amdgcn_mfma_f32_16x16x32_f16(ka[0][1], bq[1], s0, 0, 0, 0);
        s1 = __builtin_amdgcn_mfma_f32_16x16x32_f16(ka[1][0], bq[0], s1, 0, 0, 0);
        s1 = __builtin_amdgcn_mfma_f32_16x16x32_f16(ka[1][1], bq[1], s1, 0, 0, 0);
        #pragma unroll
        for (int r = 0; r < 4; ++r) {
            csum[0][r] += fexp2(s0[r]);
            csum[1][r] += fexp2(s1[r]);
        }
        __syncthreads();
    }
    #pragma unroll
    for (int kt = 0; kt < 2; ++kt)
        #pragma unroll
        for (int r = 0; r < 4; ++r) {
            csum[kt][r] += __shfl_xor(csum[kt][r], 1);
            csum[kt][r] += __shfl_xor(csum[kt][r], 2);
            csum[kt][r] += __shfl_xor(csum[kt][r], 4);
            csum[kt][r] += __shfl_xor(csum[kt][r], 8);
        }
    if (l15 == 0) {
        #pragma unroll
        for (int kt = 0; kt < 2; ++kt)
            #pragma unroll
            for (int r = 0; r < 4; ++r)
                red[wave][kt * 16 + quad * 4 + r] = csum[kt][r];
    }
    __syncthreads();
    if (t < 32)
        l_part[(size_t)z * BS + (size_t)b * SEQ + c0 + t] =
            red[0][t] + red[1][t] + red[2][t] + red[3][t];
}

// ---------------- opart[z] = P~ @ v over key-half z ----------------
// grid (64,8,2) x 256 thr (4 waves): rw=(w&1) row-tile, kw=(w>>1) key-half of
// chunk. z = key-half of sequence: 16 chunks of 64 keys, k/v DMA'd,
// double-buffered, swizzled. l = 1/(l0+l1) computed in-register with
// one-iteration prefetch. Wave-private P LDS round trip. Cross-wave O
// reduction, then COMPACT [B][S][64] f32 partial write (x16 tile is a
// separate pure-BW kernel).
__global__ __launch_bounds__(256) void out_kernel(
    const _Float16* __restrict__ qh, const _Float16* __restrict__ kh,
    const _Float16* __restrict__ vpt, const float* __restrict__ l_part,
    float* __restrict__ opart)
{
    __shared__ __align__(16) char arena[37888];
    // [0,16384)      kbuf  [2][64][64] fp16
    // [16384,32768)  vbuf  [2][64][64] fp16
    // [32768,37888)  ps    [4][16][40] fp16
    const int t = threadIdx.x, lane = t & 63, wave = t >> 6;
    const int l15 = lane & 15, quad = lane >> 4;
    const int rw = wave & 1, kw = wave >> 1;
    const int b = blockIdx.y, r0 = blockIdx.x * 32, z = blockIdx.z;
    const int kbase = z * 1024;

    half8 aq[2];
    {
        const _Float16* qp = qh + ((size_t)b * SEQ + r0 + rw * 16 + l15) * HD + quad * 8;
        aq[0] = *(const half8*)(qp);
        aq[1] = *(const half8*)(qp + 32);
    }

    auto issue = [&](int buf, int c0) {
        #pragma unroll
        for (int jj = 0; jj < 4; ++jj) {
            if (wave < 2) {        // k: 8 instrs
                const int j = wave * 4 + jj;
                const int key = j * 8 + (lane >> 3);
                const int logi = (lane & 7) ^ (key & 7);
                dma16((_Float16*)(arena + buf * 8192) + j * 512,
                      kh + ((size_t)b * SEQ + c0 + key) * HD + logi * 8);
            } else {               // v: 8 instrs (vpt is [b][d][s])
                const int j = (wave - 2) * 4 + jj;
                const int d = j * 8 + (lane >> 3);
                const int logi = (lane & 7) ^ (d & 7);
                dma16((_Float16*)(arena + 16384 + buf * 8192) + j * 512,
                      vpt + ((size_t)b * HD + d) * SEQ + c0 + logi * 8);
            }
        }
    };

    const float* lp = l_part + (size_t)b * SEQ;   // part 0; part 1 at +BS
    float lnxt[2][2];
    auto loadl = [&](int c0, float (&dst)[2][2]) {
        #pragma unroll
        for (int ct = 0; ct < 2; ++ct) {
            const int kg = c0 + kw * 32 + ct * 16 + l15;
            dst[ct][0] = lp[kg];
            dst[ct][1] = lp[BS + kg];
        }
    };

    issue(0, kbase);
    loadl(kbase, lnxt);
    __syncthreads();

    _Float16* psb = (_Float16*)(arena + 32768) + wave * 640;
    f32x4 oacc[4] = {};
    for (int it = 0; it < 16; ++it) {
        const int buf = it & 1;
        float lc[2][2];
        lc[0][0] = lnxt[0][0]; lc[0][1] = lnxt[0][1];
        lc[1][0] = lnxt[1][0]; lc[1][1] = lnxt[1][1];
        if (it + 1 < 16) {
            issue(buf ^ 1, kbase + (it + 1) * 64);
            loadl(kbase + (it + 1) * 64, lnxt);
        }
        const _Float16* kb = (const _Float16*)(arena + buf * 8192);
        const _Float16* vb = (const _Float16*)(arena + 16384 + buf * 8192);

        f32x4 s[2] = {};
        #pragma unroll
        for (int ct = 0; ct < 2; ++ct) {
            const int key = kw * 32 + ct * 16 + l15;
            #pragma unroll
            for (int kc = 0; kc < 2; ++kc) {
                half8 kf = *(const half8*)(kb + key * 64
                             + (((kc * 4 + quad) ^ (l15 & 7)) * 8));
                s[ct] = __builtin_amdgcn_mfma_f32_16x16x32_f16(aq[kc], kf, s[ct], 0, 0, 0);
            }
        }
        #pragma unroll
        for (int ct = 0; ct < 2; ++ct) {
            const float li = frcp(lc[ct][0] + lc[ct][1]);
            #pragma unroll
            for (int r = 0; r < 4; ++r)
                psb[(quad * 4 + r) * 40 + ct * 16 + l15] =
                    (_Float16)(fexp2(s[ct][r]) * li);
        }
        half8 pa = *(const half8*)(psb + l15 * 40 + quad * 8);
        #pragma unroll
        for (int n = 0; n < 4; ++n) {
            const int d = n * 16 + l15;
            half8 vf = *(const half8*)(vb + d * 64
                         + (((kw * 4 + quad) ^ (l15 & 7)) * 8));
            oacc[n] = __builtin_amdgcn_mfma_f32_16x16x32_f16(pa, vf, oacc[n], 0, 0, 0);
        }
        __syncthreads();
    }

    // cross-wave (key-half) reduction; overlay red/fin on the staging area
    float* red = (float*)(arena);            // [2][16][68]
    float* fin = (float*)(arena + 8704);     // [2][16][68] == [32][68]
    if (kw == 1) {
        #pragma unroll
        for (int n = 0; n < 4; ++n)
            #pragma unroll
            for (int r = 0; r < 4; ++r)
                red[(rw * 16 + quad * 4 + r) * 68 + n * 16 + l15] = oacc[n][r];
    }
    __syncthreads();
    if (kw == 0) {
        #pragma unroll
        for (int n = 0; n < 4; ++n)
            #pragma unroll
            for (int r = 0; r < 4; ++r)
                fin[(rw * 16 + quad * 4 + r) * 68 + n * 16 + l15] =
                    oacc[n][r] + red[(rw * 16 + quad * 4 + r) * 68 + n * 16 + l15];
    }
    __syncthreads();

    // compact epilogue: 32x64 f32 tile -> opart[z], fully coalesced float4
    const int row = t >> 3, s8 = t & 7;
    float4 u0 = *(float4*)(fin + row * 68 + s8 * 8);
    float4 u1 = *(float4*)(fin + row * 68 + s8 * 8 + 4);
    float* dst = opart + (size_t)z * ((size_t)BS * HD)
               + ((size_t)b * SEQ + r0 + row) * HD + s8 * 8;
    *(float4*)(dst)     = u0;
    *(float4*)(dst + 4) = u1;
}

// ---------------- out[b,s,h*64+d] = opart[0][b,s,d] + opart[1][b,s,d] -----
// Pure-BW broadcast: one block per (b,s) row; 256 threads cover the 1024-f32
// output row with one float4 each. Reads 8 MiB, writes 64 MiB, coalesced.
__global__ __launch_bounds__(256) void bcast_kernel(
    const float* __restrict__ opart, float* __restrict__ out)
{
    const int row = blockIdx.x;          // [0, BS)
    const int t = threadIdx.x;
    const int d = (t * 4) & 63;          // source offset within the 64-f32 O row
    const float* o0 = opart + (size_t)row * HD + d;
    const float* o1 = o0 + (size_t)BS * HD;
    float4 a = *(const float4*)o0;
    float4 c = *(const float4*)o1;
    float4 s;
    s.x = a.x + c.x; s.y = a.y + c.y; s.z = a.z + c.z; s.w = a.w + c.w;
    *(float4*)(out + (size_t)row * (HD * HEADS) + t * 4) = s;
}

extern "C" void kernel_launch(void* const* d_in, const int* in_sizes, int n_in,
                              void* d_out, int out_size, void* d_ws, size_t ws_size,
                              hipStream_t stream)
{
    const float* x  = (const float*)d_in[0];
    const float* Wq = (const float*)d_in[1];
    const float* Wk = (const float*)d_in[2];
    const float* Wv = (const float*)d_in[3];
    float* out = (float*)d_out;

    const size_t N = (size_t)BATCH * SEQ * HD;   // 1,048,576
    _Float16* qh  = (_Float16*)d_ws;
    _Float16* kh  = qh + N;
    _Float16* vpt = kh + N;
    _Float16* Wh  = vpt + N;                     // 3*64*1024 halves
    float* l_part = (float*)(Wh + 196608);       // [2][B][S] f32 (128 KB)
    float* opart  = l_part + 2 * BS;             // [2][B][S][64] f32 (8 MiB)

    wcvt_kernel <<<dim3(32, 3),    256, 0, stream>>>(Wq, Wk, Wv, Wh);
    qkv_kernel  <<<dim3(512),      512, 0, stream>>>(x, Wh, qh, kh, vpt);
    stats_kernel<<<dim3(64, 8, 2), 256, 0, stream>>>(qh, kh, l_part);
    out_kernel  <<<dim3(64, 8, 2), 256, 0, stream>>>(qh, kh, vpt, l_part, opart);
    bcast_kernel<<<dim3(BS),       256, 0, stream>>>(opart, out);
}